// Round 7
// baseline (355.487 us; speedup 1.0000x reference)
//
#include <hip/hip_runtime.h>
#include <hip/hip_fp16.h>

// MoE B=2,N=2048,C=1024,F=4096,E=8,K=2 (T=4096, slots=8192)
// Pre-packed swizzled 128x64 fp16 tiles, linear global_load_lds staging,
// serial 2-barrier K-loop. gemm1: 128x256/512thr (r6, proven). gemm2:
// 128x128/256thr kspl=2 grid=1152 (occupancy fix) + grouped decode.
// cvt kernels write dst-linear (coalesced writes, permuted 256B reads).

#define T_TOK 4096
#define C_DIM 1024
#define F_DIM 4096
#define E_NUM 8
#define BM 128
#define BN 256
#define BK 64
#define MAXT 72            // max global row-tiles: 8192/128 + 7 pad
#define NP   (MAXT * BM)   // padded positions
#define TILE_H 8192        // halfs per 128x64 tile (16KB)

typedef float f32x4 __attribute__((ext_vector_type(4)));
typedef _Float16 half8 __attribute__((ext_vector_type(8)));

#define AS1 __attribute__((address_space(1)))
#define AS3 __attribute__((address_space(3)))

__device__ __forceinline__ int swz(int r, int ec) { return ec ^ ((r & 7) << 3); }

__device__ __forceinline__ half8 cvt8(float4 f0, float4 f1) {
  half8 hv;
  hv[0] = (_Float16)f0.x; hv[1] = (_Float16)f0.y; hv[2] = (_Float16)f0.z; hv[3] = (_Float16)f0.w;
  hv[4] = (_Float16)f1.x; hv[5] = (_Float16)f1.y; hv[6] = (_Float16)f1.z; hv[7] = (_Float16)f1.w;
  return hv;
}

// bijective XCD chunk swizzle (m204)
__device__ __forceinline__ int xcd_swz(int bid, int nwg) {
  int xcd = bid & 7, rest = bid >> 3;
  int q = nwg >> 3, r = nwg & 7;
  return (xcd < r ? xcd * (q + 1) : r * (q + 1) + (xcd - r) * q) + rest;
}

// ---------------- Router
__global__ __launch_bounds__(256) void router_kernel(
    const float* __restrict__ x, const float* __restrict__ rw,
    int* __restrict__ top_idx, float* __restrict__ top_w)
{
  int t = blockIdx.x * 4 + (threadIdx.x >> 6);
  int lane = threadIdx.x & 63;
  const float* xr = x + (size_t)t * C_DIM;
  float acc[E_NUM];
#pragma unroll
  for (int e = 0; e < E_NUM; ++e) acc[e] = 0.f;
  for (int j = 0; j < C_DIM / 64; ++j) {
    int c = j * 64 + lane;
    float xv = xr[c];
#pragma unroll
    for (int e = 0; e < E_NUM; ++e) acc[e] += xv * rw[e * C_DIM + c];
  }
#pragma unroll
  for (int e = 0; e < E_NUM; ++e) {
    float v = acc[e];
#pragma unroll
    for (int off = 32; off > 0; off >>= 1) v += __shfl_xor(v, off);
    acc[e] = v;
  }
  if (lane == 0) {
    float mx = acc[0];
    for (int e = 1; e < E_NUM; ++e) mx = fmaxf(mx, acc[e]);
    float p[E_NUM]; float Z = 0.f;
    for (int e = 0; e < E_NUM; ++e) { p[e] = expf(acc[e] - mx); Z += p[e]; }
    int b0 = 0;
    for (int e = 1; e < E_NUM; ++e) if (p[e] > p[b0]) b0 = e;
    int b1i = -1; float pb = -1.f;
    for (int e = 0; e < E_NUM; ++e) if (e != b0 && p[e] > pb) { pb = p[e]; b1i = e; }
    float p0 = p[b0] / Z, p1 = pb / Z;
    float s = p0 + p1 + 1e-9f;
    top_idx[t * 2 + 0] = b0;
    top_idx[t * 2 + 1] = b1i;
    top_w[t * 2 + 0] = p0 / s;
    top_w[t * 2 + 1] = p1 / s;
  }
}

// ---------------- Lists (+ inverse map slot -> (expert, padded position))
__global__ void build_lists(const int* __restrict__ top_idx,
                            int* __restrict__ rows_g, int* __restrict__ counts,
                            int* __restrict__ tile_off, int* __restrict__ inv)
{
  int e = threadIdx.x >> 6;
  int lane = threadIdx.x & 63;
  int cnt = 0;
  for (int t0 = 0; t0 < T_TOK; t0 += 64) {
    int t = t0 + lane;
    bool sel = (top_idx[t * 2] == e) || (top_idx[t * 2 + 1] == e);
    cnt += __popcll(__ballot(sel));
  }
  if (lane == 0) counts[e] = cnt;
  __syncthreads();
  if (threadIdx.x == 0) {
    int o = 0;
    for (int i = 0; i < E_NUM; ++i) { tile_off[i] = o; o += (counts[i] + BM - 1) / BM; }
    tile_off[E_NUM] = o;
  }
  __syncthreads();
  int base = tile_off[e] * BM;
  int pos = 0;
  for (int t0 = 0; t0 < T_TOK; t0 += 64) {
    int t = t0 + lane;
    int i0 = top_idx[t * 2], i1 = top_idx[t * 2 + 1];
    bool sel = (i0 == e) || (i1 == e);
    unsigned long long mask = __ballot(sel);
    if (sel) {
      int p = pos + __popcll(mask & ((1ull << lane) - 1ull));
      int slot = t * 2 + ((i0 == e) ? 0 : 1);
      rows_g[base + p] = slot;
      inv[slot] = (e << 16) | (base + p);
    }
    pos += __popcll(mask);
  }
}

// ---------------- Gather x -> tiled swizzled fp16
__global__ __launch_bounds__(256) void gather_x(
    const float* __restrict__ x, const int* __restrict__ rows_g,
    const int* __restrict__ counts, const int* __restrict__ tile_off,
    _Float16* __restrict__ xg)
{
  unsigned g = blockIdx.x * 256 + threadIdx.x;
  unsigned p = g >> 7, ccr = g & 127;
  int gt = p >> 7, r = p & 127;
  int kc = ccr >> 3, c8 = ccr & 7;
  int e = -1;
#pragma unroll
  for (int i = 0; i < E_NUM; ++i)
    if (gt >= tile_off[i] && gt < tile_off[i + 1]) e = i;
  half8 hv = {};
  if (e >= 0) {
    int nrem = counts[e] - (gt - tile_off[e]) * BM;
    if (r < nrem) {
      int t = rows_g[p] >> 1;
      const float4* s = reinterpret_cast<const float4*>(x + (size_t)t * C_DIM + kc * 64 + c8 * 8);
      hv = cvt8(s[0], s[1]);
    }
  }
  *reinterpret_cast<half8*>(xg + ((size_t)gt * 16 + kc) * TILE_H + r * 64 + ((c8 ^ (r & 7)) << 3)) = hv;
}

// ---------------- w1 -> tiled fp16, DST-LINEAR (coalesced writes)
// dst tile index tix = (e*nftl + ftl)*16 + kc; within: r*64 + sc*8; src c8 = sc^(r&7)
__global__ __launch_bounds__(256) void cvt_w1(
    const float* __restrict__ src, _Float16* __restrict__ dst, int ch, int Fc, int lgnftl)
{
  unsigned g = blockIdx.x * 256 + threadIdx.x;   // dst 8-half chunk index
  unsigned tile = g >> 10;
  unsigned kc = tile & 15;
  unsigned et = tile >> 4;
  unsigned ftl = et & ((1u << lgnftl) - 1);
  unsigned e = et >> lgnftl;
  unsigned r = (g >> 3) & 127;
  unsigned sc = g & 7;
  unsigned c8 = sc ^ (r & 7);
  unsigned frow = ftl * 128 + r;
  const float4* s = reinterpret_cast<const float4*>(
      src + ((size_t)e * F_DIM + ch * Fc + frow) * C_DIM + kc * 64 + c8 * 8);
  *reinterpret_cast<half8*>(dst + (size_t)g * 8) = cvt8(s[0], s[1]);
}

// ---------------- w2 -> tiled fp16, DST-LINEAR
// dst tile index tix = (e*8 + ct)*nkc + kc
__global__ __launch_bounds__(256) void cvt_w2(
    const float* __restrict__ src, _Float16* __restrict__ dst, int ch, int Fc, int lgnkc)
{
  unsigned g = blockIdx.x * 256 + threadIdx.x;
  unsigned tile = g >> 10;
  unsigned kc = tile & ((1u << lgnkc) - 1);
  unsigned et = tile >> lgnkc;
  unsigned ct = et & 7;
  unsigned e = et >> 3;
  unsigned r = (g >> 3) & 127;
  unsigned sc = g & 7;
  unsigned c8 = sc ^ (r & 7);
  unsigned c = ct * 128 + r;
  const float4* s = reinterpret_cast<const float4*>(
      src + ((size_t)e * C_DIM + c) * F_DIM + ch * Fc + kc * 64 + c8 * 8);
  *reinterpret_cast<half8*>(dst + (size_t)g * 8) = cvt8(s[0], s[1]);
}

// ======== gemm1: 512-thread, 128x256 tiles (As 16KB, Bs 32KB) ========
#define STAGE_TILE(aSrc_, b0Src_, b1Src_)                                         \
  {                                                                               \
    _Pragma("unroll")                                                             \
    for (int i_ = 0; i_ < 2; ++i_) {                                              \
      int o_ = tid * 8 + i_ * 4096;                                               \
      __builtin_amdgcn_global_load_lds((const AS1 void*)((aSrc_) + o_),           \
          (AS3 void*)(&As[o_]), 16, 0, 0);                                        \
      __builtin_amdgcn_global_load_lds((const AS1 void*)((b0Src_) + o_),          \
          (AS3 void*)(&Bs[o_]), 16, 0, 0);                                        \
      __builtin_amdgcn_global_load_lds((const AS1 void*)((b1Src_) + o_),          \
          (AS3 void*)(&Bs[8192 + o_]), 16, 0, 0);                                 \
    }                                                                             \
  }

#define COMPUTE_TILE()                                                            \
  _Pragma("unroll")                                                               \
  for (int kk = 0; kk < BK; kk += 32) {                                           \
    const int klo = kk + (lane >> 4) * 8;                                         \
    half8 aF[4], bF[4];                                                           \
    _Pragma("unroll")                                                             \
    for (int m = 0; m < 4; ++m) {                                                 \
      int r = wr * 64 + m * 16 + (lane & 15);                                     \
      aF[m] = *reinterpret_cast<const half8*>(&As[r * BK + swz(r, klo)]);         \
    }                                                                             \
    _Pragma("unroll")                                                             \
    for (int n = 0; n < 4; ++n) {                                                 \
      int br = wc * 64 + n * 16 + (lane & 15);                                    \
      bF[n] = *reinterpret_cast<const half8*>(                                    \
          &Bs[(br >> 7) * 8192 + (br & 127) * 64 + swz(br, klo)]);                \
    }                                                                             \
    _Pragma("unroll")                                                             \
    for (int m = 0; m < 4; ++m)                                                   \
      _Pragma("unroll")                                                           \
      for (int n = 0; n < 4; ++n)                                                 \
        acc[m][n] = __builtin_amdgcn_mfma_f32_16x16x32_f16(aF[m], bF[n], acc[m][n], 0, 0, 0); \
  }

// ======== gemm2: 256-thread, 128x128 tiles (As 16KB, Bs 16KB) ========
#define STAGE2(aSrc_, bSrc_)                                                      \
  {                                                                               \
    _Pragma("unroll")                                                             \
    for (int i_ = 0; i_ < 4; ++i_) {                                              \
      int o_ = tid * 8 + i_ * 2048;                                               \
      __builtin_amdgcn_global_load_lds((const AS1 void*)((aSrc_) + o_),           \
          (AS3 void*)(&As[o_]), 16, 0, 0);                                        \
      __builtin_amdgcn_global_load_lds((const AS1 void*)((bSrc_) + o_),           \
          (AS3 void*)(&Bs[o_]), 16, 0, 0);                                        \
    }                                                                             \
  }

#define COMPUTE2()                                                                \
  _Pragma("unroll")                                                               \
  for (int kk = 0; kk < BK; kk += 32) {                                           \
    const int klo = kk + (lane >> 4) * 8;                                         \
    half8 aF[4], bF[4];                                                           \
    _Pragma("unroll")                                                             \
    for (int m = 0; m < 4; ++m) {                                                 \
      int r = wr * 64 + m * 16 + (lane & 15);                                     \
      aF[m] = *reinterpret_cast<const half8*>(&As[r * BK + swz(r, klo)]);         \
    }                                                                             \
    _Pragma("unroll")                                                             \
    for (int n = 0; n < 4; ++n) {                                                 \
      int r = wc * 64 + n * 16 + (lane & 15);                                     \
      bF[n] = *reinterpret_cast<const half8*>(&Bs[r * BK + swz(r, klo)]);         \
    }                                                                             \
    _Pragma("unroll")                                                             \
    for (int m = 0; m < 4; ++m)                                                   \
      _Pragma("unroll")                                                           \
      for (int n = 0; n < 4; ++n)                                                 \
        acc[m][n] = __builtin_amdgcn_mfma_f32_16x16x32_f16(aF[m], bF[n], acc[m][n], 0, 0, 0); \
  }

// ---------------- GEMM1: ht[pos, f] = relu(xg[pos] . w1t[e][f] + b1)
__global__ __launch_bounds__(512) void gemm1_kernel(
    const _Float16* __restrict__ xg, const _Float16* __restrict__ w1t,
    const float* __restrict__ b1, const int* __restrict__ counts,
    const int* __restrict__ tile_off, _Float16* __restrict__ ht,
    int ch, int Fc)
{
  const int NFT = Fc / BN;
  const int wgid = xcd_swz(blockIdx.x, gridDim.x);
  const int grp = wgid / (8 * NFT);
  const int rem = wgid - grp * 8 * NFT;
  const int ft = rem >> 3;
  const int gt = grp * 8 + (rem & 7);
  if (gt >= tile_off[E_NUM]) return;
  int e = 0;
  while (gt >= tile_off[e + 1]) ++e;
  const int nrem = min(counts[e] - (gt - tile_off[e]) * BM, BM);
  const int nftl = Fc >> 7;
  const _Float16* At  = xg + (size_t)gt * 16 * TILE_H;
  const _Float16* Bt0 = w1t + (size_t)(e * nftl + 2 * ft) * 16 * TILE_H;
  const _Float16* Bt1 = w1t + (size_t)(e * nftl + 2 * ft + 1) * 16 * TILE_H;

  __shared__ __align__(16) _Float16 As[TILE_H];
  __shared__ __align__(16) _Float16 Bs[2 * TILE_H];

  const int tid = threadIdx.x;
  const int lane = tid & 63;
  const int wave = tid >> 6;
  const int wr = wave >> 2, wc = wave & 3;

  f32x4 acc[4][4];
#pragma unroll
  for (int m = 0; m < 4; ++m)
#pragma unroll
    for (int n = 0; n < 4; ++n) acc[m][n] = (f32x4){0.f, 0.f, 0.f, 0.f};

  for (int kc = 0; kc < 16; ++kc) {
    STAGE_TILE(At + (size_t)kc * TILE_H, Bt0 + (size_t)kc * TILE_H, Bt1 + (size_t)kc * TILE_H);
    __syncthreads();
    COMPUTE_TILE();
    __syncthreads();
  }

  const int nkcF = Fc >> 6;
#pragma unroll
  for (int m = 0; m < 4; ++m) {
#pragma unroll
    for (int j = 0; j < 4; ++j) {
      int iloc = wr * 64 + m * 16 + (lane >> 4) * 4 + j;
      if (iloc < nrem) {
#pragma unroll
        for (int n = 0; n < 4; ++n) {
          int fl = ft * BN + wc * 64 + n * 16 + (lane & 15);
          float v = acc[m][n][j] + b1[e * F_DIM + ch * Fc + fl];
          _Float16 h = (_Float16)fmaxf(v, 0.f);
          ht[((size_t)gt * nkcF + (fl >> 6)) * TILE_H + iloc * 64 +
             ((((fl >> 3) & 7) ^ (iloc & 7)) << 3) + (fl & 7)] = h;
        }
      }
    }
  }
}

// ---------------- GEMM2: y[ks][pos][c] (+)= ht[pos] . w2t[e][c]
// 128x128 tiles, grid = MAXT * 8 * kspl, grouped 8-gt decode
__global__ __launch_bounds__(256) void gemm2_kernel(
    const _Float16* __restrict__ ht, const _Float16* __restrict__ w2t,
    const int* __restrict__ tile_off, _Float16* __restrict__ y,
    int Fc, int kspl, int accum)
{
  const int NCMB = 8 * kspl;
  const int wgid = xcd_swz(blockIdx.x, gridDim.x);
  const int grp = wgid / (8 * NCMB);
  const int rem = wgid - grp * 8 * NCMB;
  const int cmb = rem >> 3;
  const int gt = grp * 8 + (rem & 7);
  if (gt >= tile_off[E_NUM]) return;
  const int ct = cmb & 7;
  const int ks = cmb >> 3;
  int e = 0;
  while (gt >= tile_off[e + 1]) ++e;
  const int nkc = Fc >> 6;
  const int klen = nkc / kspl;
  const _Float16* At = ht + ((size_t)gt * nkc + ks * klen) * TILE_H;
  const _Float16* Bt = w2t + ((size_t)(e * 8 + ct) * nkc + ks * klen) * TILE_H;

  __shared__ __align__(16) _Float16 As[TILE_H];
  __shared__ __align__(16) _Float16 Bs[TILE_H];

  const int tid = threadIdx.x;
  const int lane = tid & 63;
  const int wave = tid >> 6;
  const int wr = wave >> 1, wc = wave & 1;

  f32x4 acc[4][4];
#pragma unroll
  for (int m = 0; m < 4; ++m)
#pragma unroll
    for (int n = 0; n < 4; ++n) acc[m][n] = (f32x4){0.f, 0.f, 0.f, 0.f};

  for (int kc = 0; kc < klen; ++kc) {
    STAGE2(At + (size_t)kc * TILE_H, Bt + (size_t)kc * TILE_H);
    __syncthreads();
    COMPUTE2();
    __syncthreads();
  }

  _Float16* yk = y + ((size_t)(ks * MAXT + gt) * BM) * C_DIM;
#pragma unroll
  for (int m = 0; m < 4; ++m) {
#pragma unroll
    for (int j = 0; j < 4; ++j) {
      int iloc = wr * 64 + m * 16 + (lane >> 4) * 4 + j;
#pragma unroll
      for (int n = 0; n < 4; ++n) {
        int c = ct * 128 + wc * 64 + n * 16 + (lane & 15);
        _Float16* p = yk + (size_t)iloc * C_DIM + c;
        float v = acc[m][n][j];
        if (accum) v += (float)*p;
        *p = (_Float16)v;
      }
    }
  }
}

// ---------------- Combine: out[t] = sum_k w_k * (b2[e_k] + sum_ks y[ks][pos_k])
__global__ __launch_bounds__(256) void combine_kernel(
    const _Float16* __restrict__ y, const int* __restrict__ inv,
    const float* __restrict__ top_w, const float* __restrict__ b2,
    float* __restrict__ out, int kspl)
{
  int g = blockIdx.x * 256 + threadIdx.x;
  int t = g >> 7, c8 = (g & 127) << 3;
  float o[8];
#pragma unroll
  for (int i = 0; i < 8; ++i) o[i] = 0.f;
#pragma unroll
  for (int k = 0; k < 2; ++k) {
    int iv = inv[t * 2 + k];
    int e = iv >> 16, pos = iv & 0xffff;
    float w = top_w[t * 2 + k];
    const float4* bb = reinterpret_cast<const float4*>(b2 + e * C_DIM + c8);
    float4 bv0 = bb[0], bv1 = bb[1];
    float s[8] = {bv0.x, bv0.y, bv0.z, bv0.w, bv1.x, bv1.y, bv1.z, bv1.w};
    for (int ks = 0; ks < kspl; ++ks) {
      half8 hv = *reinterpret_cast<const half8*>(
          y + ((size_t)(ks * MAXT * BM + pos)) * C_DIM + c8);
#pragma unroll
      for (int i = 0; i < 8; ++i) s[i] += (float)hv[i];
    }
#pragma unroll
    for (int i = 0; i < 8; ++i) o[i] += w * s[i];
  }
  float4* op = reinterpret_cast<float4*>(out + (size_t)t * C_DIM + c8);
  op[0] = (float4){o[0], o[1], o[2], o[3]};
  op[1] = (float4){o[4], o[5], o[6], o[7]};
}

extern "C" void kernel_launch(void* const* d_in, const int* in_sizes, int n_in,
                              void* d_out, int out_size, void* d_ws, size_t ws_size,
                              hipStream_t stream)
{
  const float* x  = (const float*)d_in[0];
  const float* rw = (const float*)d_in[1];
  const float* w1 = (const float*)d_in[2];
  const float* b1 = (const float*)d_in[3];
  const float* w2 = (const float*)d_in[4];
  const float* b2 = (const float*)d_in[5];
  float* out = (float*)d_out;

  char* ws = (char*)d_ws;
  size_t off = 0;
  auto carve = [&](size_t bytes) -> void* {
    void* p = ws + off;
    off += (bytes + 255) & ~(size_t)255;
    return p;
  };
  int*   top_idx  = (int*)carve((size_t)T_TOK * 2 * sizeof(int));
  float* top_w    = (float*)carve((size_t)T_TOK * 2 * sizeof(float));
  int*   counts   = (int*)carve(E_NUM * sizeof(int));
  int*   tile_off = (int*)carve((E_NUM + 1) * sizeof(int));
  int*   rows_g   = (int*)carve((size_t)NP * sizeof(int));
  int*   inv      = (int*)carve((size_t)T_TOK * 2 * sizeof(int));
  _Float16* xg    = (_Float16*)carve((size_t)MAXT * 16 * TILE_H * sizeof(_Float16));
  _Float16* y     = (_Float16*)carve((size_t)2 * NP * C_DIM * sizeof(_Float16));
  size_t fixed = off;

  int nchunk = 8;
  const int cands[4] = {1, 2, 4, 8};
  for (int ci = 0; ci < 4; ++ci) {
    int n = cands[ci];
    size_t fc = (size_t)(F_DIM / n);
    size_t w1b = ((size_t)E_NUM * fc * C_DIM * 2 + 255) & ~(size_t)255;
    size_t w2b = ((size_t)E_NUM * C_DIM * fc * 2 + 255) & ~(size_t)255;
    size_t htb = ((size_t)MAXT * (fc >> 6) * TILE_H * 2 + 255) & ~(size_t)255;
    if (fixed + w1b + w2b + htb <= ws_size) { nchunk = n; break; }
  }
  const int Fc = F_DIM / nchunk;
  int lgFc = 0; while ((1 << lgFc) < Fc) ++lgFc;
  _Float16* w1t = (_Float16*)carve((size_t)E_NUM * Fc * C_DIM * sizeof(_Float16));
  _Float16* w2t = (_Float16*)carve((size_t)E_NUM * C_DIM * Fc * sizeof(_Float16));
  _Float16* ht  = (_Float16*)carve((size_t)MAXT * (Fc >> 6) * TILE_H * sizeof(_Float16));

  const int kspl = (Fc >= 2048) ? 2 : 1;

  router_kernel<<<T_TOK / 4, 256, 0, stream>>>(x, rw, top_idx, top_w);
  build_lists<<<1, 512, 0, stream>>>(top_idx, rows_g, counts, tile_off, inv);
  gather_x<<<(MAXT * BM * 128) / 256, 256, 0, stream>>>(x, rows_g, counts, tile_off, xg);

  const int cvt_blocks = 4 * Fc;   // E*Fc*C/8 chunks / 256 threads
  for (int ch = 0; ch < nchunk; ++ch) {
    cvt_w1<<<cvt_blocks, 256, 0, stream>>>(w1, w1t, ch, Fc, lgFc - 7);
    cvt_w2<<<cvt_blocks, 256, 0, stream>>>(w2, w2t, ch, Fc, lgFc - 6);
    gemm1_kernel<<<MAXT * (Fc / BN), 512, 0, stream>>>(
        xg, w1t, b1, counts, tile_off, ht, ch, Fc);
    gemm2_kernel<<<MAXT * 8 * kspl, 256, 0, stream>>>(
        ht, w2t, tile_off, y, Fc, kspl, ch != 0);
  }
  combine_kernel<<<(T_TOK * 128) / 256, 256, 0, stream>>>(y, inv, top_w, b2, out, kspl);
}

// Round 8
// 352.714 us; speedup vs baseline: 1.0079x; 1.0079x over previous
//
#include <hip/hip_runtime.h>
#include <hip/hip_fp16.h>

// MoE B=2,N=2048,C=1024,F=4096,E=8,K=2 (T=4096, slots=8192)
// Pre-packed swizzled 128x64 fp16 tiles, linear global_load_lds staging,
// serial 2-barrier K-loop. SWAPPED-OPERAND MFMA (D rows = f/c, cols = tokens)
// so epilogue C-stores are 8B vector stores instead of 2B scalar stores.
// gemm1: 128x256/512thr; gemm2: 128x128/256thr kspl=2. Merged cvt kernel.

#define T_TOK 4096
#define C_DIM 1024
#define F_DIM 4096
#define E_NUM 8
#define BM 128
#define BN 256
#define BK 64
#define MAXT 72            // max global row-tiles: 8192/128 + 7 pad
#define NP   (MAXT * BM)   // padded positions
#define TILE_H 8192        // halfs per 128x64 tile (16KB)

typedef float f32x4 __attribute__((ext_vector_type(4)));
typedef _Float16 half8 __attribute__((ext_vector_type(8)));
typedef _Float16 half4 __attribute__((ext_vector_type(4)));

#define AS1 __attribute__((address_space(1)))
#define AS3 __attribute__((address_space(3)))

__device__ __forceinline__ int swz(int r, int ec) { return ec ^ ((r & 7) << 3); }

__device__ __forceinline__ half8 cvt8(float4 f0, float4 f1) {
  half8 hv;
  hv[0] = (_Float16)f0.x; hv[1] = (_Float16)f0.y; hv[2] = (_Float16)f0.z; hv[3] = (_Float16)f0.w;
  hv[4] = (_Float16)f1.x; hv[5] = (_Float16)f1.y; hv[6] = (_Float16)f1.z; hv[7] = (_Float16)f1.w;
  return hv;
}

// bijective XCD chunk swizzle (m204)
__device__ __forceinline__ int xcd_swz(int bid, int nwg) {
  int xcd = bid & 7, rest = bid >> 3;
  int q = nwg >> 3, r = nwg & 7;
  return (xcd < r ? xcd * (q + 1) : r * (q + 1) + (xcd - r) * q) + rest;
}

// ---------------- Router
__global__ __launch_bounds__(256) void router_kernel(
    const float* __restrict__ x, const float* __restrict__ rw,
    int* __restrict__ top_idx, float* __restrict__ top_w)
{
  int t = blockIdx.x * 4 + (threadIdx.x >> 6);
  int lane = threadIdx.x & 63;
  const float* xr = x + (size_t)t * C_DIM;
  float acc[E_NUM];
#pragma unroll
  for (int e = 0; e < E_NUM; ++e) acc[e] = 0.f;
  for (int j = 0; j < C_DIM / 64; ++j) {
    int c = j * 64 + lane;
    float xv = xr[c];
#pragma unroll
    for (int e = 0; e < E_NUM; ++e) acc[e] += xv * rw[e * C_DIM + c];
  }
#pragma unroll
  for (int e = 0; e < E_NUM; ++e) {
    float v = acc[e];
#pragma unroll
    for (int off = 32; off > 0; off >>= 1) v += __shfl_xor(v, off);
    acc[e] = v;
  }
  if (lane == 0) {
    float mx = acc[0];
    for (int e = 1; e < E_NUM; ++e) mx = fmaxf(mx, acc[e]);
    float p[E_NUM]; float Z = 0.f;
    for (int e = 0; e < E_NUM; ++e) { p[e] = expf(acc[e] - mx); Z += p[e]; }
    int b0 = 0;
    for (int e = 1; e < E_NUM; ++e) if (p[e] > p[b0]) b0 = e;
    int b1i = -1; float pb = -1.f;
    for (int e = 0; e < E_NUM; ++e) if (e != b0 && p[e] > pb) { pb = p[e]; b1i = e; }
    float p0 = p[b0] / Z, p1 = pb / Z;
    float s = p0 + p1 + 1e-9f;
    top_idx[t * 2 + 0] = b0;
    top_idx[t * 2 + 1] = b1i;
    top_w[t * 2 + 0] = p0 / s;
    top_w[t * 2 + 1] = p1 / s;
  }
}

// ---------------- Lists (+ inverse map slot -> (expert, padded position))
__global__ void build_lists(const int* __restrict__ top_idx,
                            int* __restrict__ rows_g, int* __restrict__ counts,
                            int* __restrict__ tile_off, int* __restrict__ inv)
{
  int e = threadIdx.x >> 6;
  int lane = threadIdx.x & 63;
  int cnt = 0;
  for (int t0 = 0; t0 < T_TOK; t0 += 64) {
    int t = t0 + lane;
    bool sel = (top_idx[t * 2] == e) || (top_idx[t * 2 + 1] == e);
    cnt += __popcll(__ballot(sel));
  }
  if (lane == 0) counts[e] = cnt;
  __syncthreads();
  if (threadIdx.x == 0) {
    int o = 0;
    for (int i = 0; i < E_NUM; ++i) { tile_off[i] = o; o += (counts[i] + BM - 1) / BM; }
    tile_off[E_NUM] = o;
  }
  __syncthreads();
  int base = tile_off[e] * BM;
  int pos = 0;
  for (int t0 = 0; t0 < T_TOK; t0 += 64) {
    int t = t0 + lane;
    int i0 = top_idx[t * 2], i1 = top_idx[t * 2 + 1];
    bool sel = (i0 == e) || (i1 == e);
    unsigned long long mask = __ballot(sel);
    if (sel) {
      int p = pos + __popcll(mask & ((1ull << lane) - 1ull));
      int slot = t * 2 + ((i0 == e) ? 0 : 1);
      rows_g[base + p] = slot;
      inv[slot] = (e << 16) | (base + p);
    }
    pos += __popcll(mask);
  }
}

// ---------------- Gather x -> tiled swizzled fp16
__global__ __launch_bounds__(256) void gather_x(
    const float* __restrict__ x, const int* __restrict__ rows_g,
    const int* __restrict__ counts, const int* __restrict__ tile_off,
    _Float16* __restrict__ xg)
{
  unsigned g = blockIdx.x * 256 + threadIdx.x;
  unsigned p = g >> 7, ccr = g & 127;
  int gt = p >> 7, r = p & 127;
  int kc = ccr >> 3, c8 = ccr & 7;
  int e = -1;
#pragma unroll
  for (int i = 0; i < E_NUM; ++i)
    if (gt >= tile_off[i] && gt < tile_off[i + 1]) e = i;
  half8 hv = {};
  if (e >= 0) {
    int nrem = counts[e] - (gt - tile_off[e]) * BM;
    if (r < nrem) {
      int t = rows_g[p] >> 1;
      const float4* s = reinterpret_cast<const float4*>(x + (size_t)t * C_DIM + kc * 64 + c8 * 8);
      hv = cvt8(s[0], s[1]);
    }
  }
  *reinterpret_cast<half8*>(xg + ((size_t)gt * 16 + kc) * TILE_H + r * 64 + ((c8 ^ (r & 7)) << 3)) = hv;
}

// ---------------- merged w1+w2 -> tiled fp16, DST-LINEAR (coalesced writes)
__global__ __launch_bounds__(256) void cvt_w(
    const float* __restrict__ w1, const float* __restrict__ w2,
    _Float16* __restrict__ w1t, _Float16* __restrict__ w2t,
    int ch, int Fc, int lgnftl, int lgnkc, unsigned halfChunks)
{
  unsigned g = blockIdx.x * 256 + threadIdx.x;
  if (g < halfChunks) {
    // w1 [E][F][C] -> [e][ftl][kc(16)][128][64] swizzled
    unsigned tile = g >> 10;
    unsigned kc = tile & 15;
    unsigned et = tile >> 4;
    unsigned ftl = et & ((1u << lgnftl) - 1);
    unsigned e = et >> lgnftl;
    unsigned r = (g >> 3) & 127;
    unsigned sc = g & 7;
    unsigned c8 = sc ^ (r & 7);
    unsigned frow = ftl * 128 + r;
    const float4* s = reinterpret_cast<const float4*>(
        w1 + ((size_t)e * F_DIM + ch * Fc + frow) * C_DIM + kc * 64 + c8 * 8);
    *reinterpret_cast<half8*>(w1t + (size_t)g * 8) = cvt8(s[0], s[1]);
  } else {
    // w2 [E][C][F] -> [e][ct(8)][kc(nkc)][128][64] swizzled
    unsigned g2 = g - halfChunks;
    unsigned tile = g2 >> 10;
    unsigned kc = tile & ((1u << lgnkc) - 1);
    unsigned et = tile >> lgnkc;
    unsigned ct = et & 7;
    unsigned e = et >> 3;
    unsigned r = (g2 >> 3) & 127;
    unsigned sc = g2 & 7;
    unsigned c8 = sc ^ (r & 7);
    unsigned c = ct * 128 + r;
    const float4* s = reinterpret_cast<const float4*>(
        w2 + ((size_t)e * C_DIM + c) * F_DIM + ch * Fc + kc * 64 + c8 * 8);
    *reinterpret_cast<half8*>(w2t + (size_t)g2 * 8) = cvt8(s[0], s[1]);
  }
}

// ======== gemm1: 512-thread, 128x256 tiles (As 16KB, Bs 32KB) ========
#define STAGE_TILE(aSrc_, b0Src_, b1Src_)                                         \
  {                                                                               \
    _Pragma("unroll")                                                             \
    for (int i_ = 0; i_ < 2; ++i_) {                                              \
      int o_ = tid * 8 + i_ * 4096;                                               \
      __builtin_amdgcn_global_load_lds((const AS1 void*)((aSrc_) + o_),           \
          (AS3 void*)(&As[o_]), 16, 0, 0);                                        \
      __builtin_amdgcn_global_load_lds((const AS1 void*)((b0Src_) + o_),          \
          (AS3 void*)(&Bs[o_]), 16, 0, 0);                                        \
      __builtin_amdgcn_global_load_lds((const AS1 void*)((b1Src_) + o_),          \
          (AS3 void*)(&Bs[8192 + o_]), 16, 0, 0);                                 \
    }                                                                             \
  }

// SWAPPED operands: mfma(bF, aF) -> D rows = f (reg-indexed), cols = tokens (lane&15)
#define COMPUTE_TILE()                                                            \
  _Pragma("unroll")                                                               \
  for (int kk = 0; kk < BK; kk += 32) {                                           \
    const int klo = kk + (lane >> 4) * 8;                                         \
    half8 aF[4], bF[4];                                                           \
    _Pragma("unroll")                                                             \
    for (int m = 0; m < 4; ++m) {                                                 \
      int r = wr * 64 + m * 16 + (lane & 15);                                     \
      aF[m] = *reinterpret_cast<const half8*>(&As[r * BK + swz(r, klo)]);         \
    }                                                                             \
    _Pragma("unroll")                                                             \
    for (int n = 0; n < 4; ++n) {                                                 \
      int br = wc * 64 + n * 16 + (lane & 15);                                    \
      bF[n] = *reinterpret_cast<const half8*>(                                    \
          &Bs[(br >> 7) * 8192 + (br & 127) * 64 + swz(br, klo)]);                \
    }                                                                             \
    _Pragma("unroll")                                                             \
    for (int m = 0; m < 4; ++m)                                                   \
      _Pragma("unroll")                                                           \
      for (int n = 0; n < 4; ++n)                                                 \
        acc[m][n] = __builtin_amdgcn_mfma_f32_16x16x32_f16(bF[n], aF[m], acc[m][n], 0, 0, 0); \
  }

// ======== gemm2: 256-thread, 128x128 tiles (As 16KB, Bs 16KB) ========
#define STAGE2(aSrc_, bSrc_)                                                      \
  {                                                                               \
    _Pragma("unroll")                                                             \
    for (int i_ = 0; i_ < 4; ++i_) {                                              \
      int o_ = tid * 8 + i_ * 2048;                                               \
      __builtin_amdgcn_global_load_lds((const AS1 void*)((aSrc_) + o_),           \
          (AS3 void*)(&As[o_]), 16, 0, 0);                                        \
      __builtin_amdgcn_global_load_lds((const AS1 void*)((bSrc_) + o_),           \
          (AS3 void*)(&Bs[o_]), 16, 0, 0);                                        \
    }                                                                             \
  }

#define COMPUTE2()                                                                \
  _Pragma("unroll")                                                               \
  for (int kk = 0; kk < BK; kk += 32) {                                           \
    const int klo = kk + (lane >> 4) * 8;                                         \
    half8 aF[4], bF[4];                                                           \
    _Pragma("unroll")                                                             \
    for (int m = 0; m < 4; ++m) {                                                 \
      int r = wr * 64 + m * 16 + (lane & 15);                                     \
      aF[m] = *reinterpret_cast<const half8*>(&As[r * BK + swz(r, klo)]);         \
    }                                                                             \
    _Pragma("unroll")                                                             \
    for (int n = 0; n < 4; ++n) {                                                 \
      int r = wc * 64 + n * 16 + (lane & 15);                                     \
      bF[n] = *reinterpret_cast<const half8*>(&Bs[r * BK + swz(r, klo)]);         \
    }                                                                             \
    _Pragma("unroll")                                                             \
    for (int m = 0; m < 4; ++m)                                                   \
      _Pragma("unroll")                                                           \
      for (int n = 0; n < 4; ++n)                                                 \
        acc[m][n] = __builtin_amdgcn_mfma_f32_16x16x32_f16(bF[n], aF[m], acc[m][n], 0, 0, 0); \
  }

// ---------------- GEMM1: ht[pos, f] = relu(xg[pos] . w1t[e][f] + b1)
__global__ __launch_bounds__(512) void gemm1_kernel(
    const _Float16* __restrict__ xg, const _Float16* __restrict__ w1t,
    const float* __restrict__ b1, const int* __restrict__ counts,
    const int* __restrict__ tile_off, _Float16* __restrict__ ht,
    int ch, int Fc)
{
  const int NFT = Fc / BN;
  const int wgid = xcd_swz(blockIdx.x, gridDim.x);
  const int grp = wgid / (8 * NFT);
  const int rem = wgid - grp * 8 * NFT;
  const int ft = rem >> 3;
  const int gt = grp * 8 + (rem & 7);
  if (gt >= tile_off[E_NUM]) return;
  int e = 0;
  while (gt >= tile_off[e + 1]) ++e;
  const int nftl = Fc >> 7;
  const _Float16* At  = xg + (size_t)gt * 16 * TILE_H;
  const _Float16* Bt0 = w1t + (size_t)(e * nftl + 2 * ft) * 16 * TILE_H;
  const _Float16* Bt1 = w1t + (size_t)(e * nftl + 2 * ft + 1) * 16 * TILE_H;

  __shared__ __align__(16) _Float16 As[TILE_H];
  __shared__ __align__(16) _Float16 Bs[2 * TILE_H];

  const int tid = threadIdx.x;
  const int lane = tid & 63;
  const int wave = tid >> 6;
  const int wr = wave >> 2, wc = wave & 3;

  f32x4 acc[4][4];
#pragma unroll
  for (int m = 0; m < 4; ++m)
#pragma unroll
    for (int n = 0; n < 4; ++n) acc[m][n] = (f32x4){0.f, 0.f, 0.f, 0.f};

  for (int kc = 0; kc < 16; ++kc) {
    STAGE_TILE(At + (size_t)kc * TILE_H, Bt0 + (size_t)kc * TILE_H, Bt1 + (size_t)kc * TILE_H);
    __syncthreads();
    COMPUTE_TILE();
    __syncthreads();
  }

  // epilogue: lane holds 4 consecutive f per acc reg -> 8B stores
  const int nkcF = Fc >> 6;
  const float* b1e = b1 + e * F_DIM + ch * Fc;
#pragma unroll
  for (int m = 0; m < 4; ++m) {
    int tok = wr * 64 + m * 16 + (lane & 15);   // pad rows written too (finite, never read)
#pragma unroll
    for (int n = 0; n < 4; ++n) {
      int flb = ft * BN + wc * 64 + n * 16 + ((lane >> 4) << 2);
      float4 bv = *reinterpret_cast<const float4*>(b1e + flb);
      half4 hv;
      hv[0] = (_Float16)fmaxf(acc[m][n][0] + bv.x, 0.f);
      hv[1] = (_Float16)fmaxf(acc[m][n][1] + bv.y, 0.f);
      hv[2] = (_Float16)fmaxf(acc[m][n][2] + bv.z, 0.f);
      hv[3] = (_Float16)fmaxf(acc[m][n][3] + bv.w, 0.f);
      *reinterpret_cast<half4*>(
          ht + ((size_t)gt * nkcF + (flb >> 6)) * TILE_H + tok * 64 +
          ((((flb >> 3) & 7) ^ (tok & 7)) << 3) + (flb & 7)) = hv;
    }
  }
}

// ---------------- GEMM2: y[ks][pos][c] (+)= ht[pos] . w2t[e][c]
__global__ __launch_bounds__(256) void gemm2_kernel(
    const _Float16* __restrict__ ht, const _Float16* __restrict__ w2t,
    const int* __restrict__ tile_off, _Float16* __restrict__ y,
    int Fc, int kspl, int accum)
{
  const int NCMB = 8 * kspl;
  const int wgid = xcd_swz(blockIdx.x, gridDim.x);
  const int grp = wgid / (8 * NCMB);
  const int rem = wgid - grp * 8 * NCMB;
  const int cmb = rem >> 3;
  const int gt = grp * 8 + (rem & 7);
  if (gt >= tile_off[E_NUM]) return;
  const int ct = cmb & 7;
  const int ks = cmb >> 3;
  int e = 0;
  while (gt >= tile_off[e + 1]) ++e;
  const int nkc = Fc >> 6;
  const int klen = nkc / kspl;
  const _Float16* At = ht + ((size_t)gt * nkc + ks * klen) * TILE_H;
  const _Float16* Bt = w2t + ((size_t)(e * 8 + ct) * nkc + ks * klen) * TILE_H;

  __shared__ __align__(16) _Float16 As[TILE_H];
  __shared__ __align__(16) _Float16 Bs[TILE_H];

  const int tid = threadIdx.x;
  const int lane = tid & 63;
  const int wave = tid >> 6;
  const int wr = wave >> 1, wc = wave & 1;

  f32x4 acc[4][4];
#pragma unroll
  for (int m = 0; m < 4; ++m)
#pragma unroll
    for (int n = 0; n < 4; ++n) acc[m][n] = (f32x4){0.f, 0.f, 0.f, 0.f};

  for (int kc = 0; kc < klen; ++kc) {
    STAGE2(At + (size_t)kc * TILE_H, Bt + (size_t)kc * TILE_H);
    __syncthreads();
    COMPUTE2();
    __syncthreads();
  }

  // epilogue: lane holds 4 consecutive c per acc reg -> 8B stores
  _Float16* yk = y + ((size_t)(ks * MAXT + gt) * BM) * C_DIM;
#pragma unroll
  for (int m = 0; m < 4; ++m) {
    int pos = wr * 64 + m * 16 + (lane & 15);
#pragma unroll
    for (int n = 0; n < 4; ++n) {
      int cb = ct * 128 + wc * 64 + n * 16 + ((lane >> 4) << 2);
      half4* p = reinterpret_cast<half4*>(yk + (size_t)pos * C_DIM + cb);
      half4 hv;
      if (accum) {
        half4 old = *p;
        hv[0] = (_Float16)(acc[m][n][0] + (float)old[0]);
        hv[1] = (_Float16)(acc[m][n][1] + (float)old[1]);
        hv[2] = (_Float16)(acc[m][n][2] + (float)old[2]);
        hv[3] = (_Float16)(acc[m][n][3] + (float)old[3]);
      } else {
        hv[0] = (_Float16)acc[m][n][0];
        hv[1] = (_Float16)acc[m][n][1];
        hv[2] = (_Float16)acc[m][n][2];
        hv[3] = (_Float16)acc[m][n][3];
      }
      *p = hv;
    }
  }
}

// ---------------- Combine: out[t] = sum_k w_k * (b2[e_k] + sum_ks y[ks][pos_k])
__global__ __launch_bounds__(256) void combine_kernel(
    const _Float16* __restrict__ y, const int* __restrict__ inv,
    const float* __restrict__ top_w, const float* __restrict__ b2,
    float* __restrict__ out, int kspl)
{
  int g = blockIdx.x * 256 + threadIdx.x;
  int t = g >> 7, c8 = (g & 127) << 3;
  float o[8];
#pragma unroll
  for (int i = 0; i < 8; ++i) o[i] = 0.f;
#pragma unroll
  for (int k = 0; k < 2; ++k) {
    int iv = inv[t * 2 + k];
    int e = iv >> 16, pos = iv & 0xffff;
    float w = top_w[t * 2 + k];
    const float4* bb = reinterpret_cast<const float4*>(b2 + e * C_DIM + c8);
    float4 bv0 = bb[0], bv1 = bb[1];
    float s[8] = {bv0.x, bv0.y, bv0.z, bv0.w, bv1.x, bv1.y, bv1.z, bv1.w};
    for (int ks = 0; ks < kspl; ++ks) {
      half8 hv = *reinterpret_cast<const half8*>(
          y + ((size_t)(ks * MAXT * BM + pos)) * C_DIM + c8);
#pragma unroll
      for (int i = 0; i < 8; ++i) s[i] += (float)hv[i];
    }
#pragma unroll
    for (int i = 0; i < 8; ++i) o[i] += w * s[i];
  }
  float4* op = reinterpret_cast<float4*>(out + (size_t)t * C_DIM + c8);
  op[0] = (float4){o[0], o[1], o[2], o[3]};
  op[1] = (float4){o[4], o[5], o[6], o[7]};
}

extern "C" void kernel_launch(void* const* d_in, const int* in_sizes, int n_in,
                              void* d_out, int out_size, void* d_ws, size_t ws_size,
                              hipStream_t stream)
{
  const float* x  = (const float*)d_in[0];
  const float* rw = (const float*)d_in[1];
  const float* w1 = (const float*)d_in[2];
  const float* b1 = (const float*)d_in[3];
  const float* w2 = (const float*)d_in[4];
  const float* b2 = (const float*)d_in[5];
  float* out = (float*)d_out;

  char* ws = (char*)d_ws;
  size_t off = 0;
  auto carve = [&](size_t bytes) -> void* {
    void* p = ws + off;
    off += (bytes + 255) & ~(size_t)255;
    return p;
  };
  int*   top_idx  = (int*)carve((size_t)T_TOK * 2 * sizeof(int));
  float* top_w    = (float*)carve((size_t)T_TOK * 2 * sizeof(float));
  int*   counts   = (int*)carve(E_NUM * sizeof(int));
  int*   tile_off = (int*)carve((E_NUM + 1) * sizeof(int));
  int*   rows_g   = (int*)carve((size_t)NP * sizeof(int));
  int*   inv      = (int*)carve((size_t)T_TOK * 2 * sizeof(int));
  _Float16* xg    = (_Float16*)carve((size_t)MAXT * 16 * TILE_H * sizeof(_Float16));
  _Float16* y     = (_Float16*)carve((size_t)2 * NP * C_DIM * sizeof(_Float16));
  size_t fixed = off;

  int nchunk = 8;
  const int cands[4] = {1, 2, 4, 8};
  for (int ci = 0; ci < 4; ++ci) {
    int n = cands[ci];
    size_t fc = (size_t)(F_DIM / n);
    size_t w1b = ((size_t)E_NUM * fc * C_DIM * 2 + 255) & ~(size_t)255;
    size_t w2b = ((size_t)E_NUM * C_DIM * fc * 2 + 255) & ~(size_t)255;
    size_t htb = ((size_t)MAXT * (fc >> 6) * TILE_H * 2 + 255) & ~(size_t)255;
    if (fixed + w1b + w2b + htb <= ws_size) { nchunk = n; break; }
  }
  const int Fc = F_DIM / nchunk;
  int lgFc = 0; while ((1 << lgFc) < Fc) ++lgFc;
  _Float16* w1t = (_Float16*)carve((size_t)E_NUM * Fc * C_DIM * sizeof(_Float16));
  _Float16* w2t = (_Float16*)carve((size_t)E_NUM * C_DIM * Fc * sizeof(_Float16));
  _Float16* ht  = (_Float16*)carve((size_t)MAXT * (Fc >> 6) * TILE_H * sizeof(_Float16));

  const int kspl = (Fc >= 2048) ? 2 : 1;

  router_kernel<<<T_TOK / 4, 256, 0, stream>>>(x, rw, top_idx, top_w);
  build_lists<<<1, 512, 0, stream>>>(top_idx, rows_g, counts, tile_off, inv);
  gather_x<<<(MAXT * BM * 128) / 256, 256, 0, stream>>>(x, rows_g, counts, tile_off, xg);

  const unsigned halfChunks = (unsigned)Fc << 10;   // E*Fc*C/8
  for (int ch = 0; ch < nchunk; ++ch) {
    cvt_w<<<8 * Fc, 256, 0, stream>>>(w1, w2, w1t, w2t, ch, Fc, lgFc - 7, lgFc - 6, halfChunks);
    gemm1_kernel<<<MAXT * (Fc / BN), 512, 0, stream>>>(
        xg, w1t, b1, counts, tile_off, ht, ch, Fc);
    gemm2_kernel<<<MAXT * 8 * kspl, 256, 0, stream>>>(
        ht, w2t, tile_off, y, Fc, kspl, ch != 0);
  }
  combine_kernel<<<(T_TOK * 128) / 256, 256, 0, stream>>>(y, inv, top_w, b2, out, kspl);
}